// Round 12
// baseline (142.419 us; speedup 1.0000x reference)
//
#include <hip/hip_runtime.h>
#include <hip/hip_bf16.h>
#include <math.h>

typedef __attribute__((ext_vector_type(8))) short short8;   // 8 bf16 = 4 VGPRs (MFMA A/B frag)
typedef __attribute__((ext_vector_type(4))) float floatx4;  // MFMA C/D frag
typedef __attribute__((ext_vector_type(2))) float floatx2;

#define NB 256

// ---------------- workspace layout (bytes) ----------------
#define WPB_OFF 0u        // 32*288 bf16 [oc][k=n*32+ic], rows>=18 zero (p_conv, unscaled)
#define W2B_OFF 18432u    // 32*288 bf16, scaled by inv2[oc]
#define W3B_OFF 36864u    // 64*288 bf16, scaled by inv3[oc]
#define W1B_OFF 73728u    // 32*32 bf16 [oc][k=n*3+ic], k>=27 zero, scaled by inv1[oc]
#define C1S_OFF 75776u    // 32 f32 shift1
#define C2S_OFF 75904u    // 32 f32 shift2
#define C3S_OFF 76032u    // 64 f32 shift3

// ---------------- LDS layout (bytes) ----------------
#define L_IMG1 0            // 785*64 = 50240  (h1: 784 px + zero slot, granule-swizzled)
#define L_U    50240        // 785*64 = 50240  (x staging, then h2 interior + zero slot, swizzled)
#define L_OFFT 100480       // w1 stash (2KB), then per-wave offsets [12][288]f32, then part[12][32]
#define L_WL   114304       // 64 rows * 592 B (wp+w2 rows, later w3 rows)
#define L_TOT  152192

static __device__ __forceinline__ unsigned short f2bf(float f) {
    unsigned u = __float_as_uint(f);
    u = (u + 0x7fffu + ((u >> 16) & 1u)) >> 16;   // RNE
    return (unsigned short)u;
}

static __device__ __forceinline__ unsigned pk2bf(float a, float b) {
    __hip_bfloat162 h = __float22bfloat162_rn(make_float2(a, b));
    unsigned r;
    __builtin_memcpy(&r, &h, 4);
    return r;
}

static __device__ __forceinline__ floatx2 up2(unsigned u) {
    floatx2 r;
    r.x = __uint_as_float(u << 16);
    r.y = __uint_as_float(u & 0xffff0000u);
    return r;
}

// 64-B pixel stride, 16-B granule rotated by (px>>1):
// bank-group = (4*px + (s + px>>1)&3) mod 8 — uniform over all 8 groups as px varies.
static __device__ __forceinline__ int sw64(int px, int s) {
    return px * 64 + (((s + (px >> 1)) & 3) << 4);
}
// byte address of 2-byte channel ch (0..31) in pixel px
static __device__ __forceinline__ int sw64ch(int px, int ch) {
    return px * 64 + ((((ch >> 3) + (px >> 1)) & 3) << 4) + ((ch & 7) << 1);
}

// ------- weight prep: bf16, pre-transposed, BN-scale-folded -------
__global__ void wcvt(const float* __restrict__ wp, const float* __restrict__ w2,
                     const float* __restrict__ w3, const float* __restrict__ w1,
                     const float* __restrict__ g1, const float* __restrict__ b1,
                     const float* __restrict__ m1, const float* __restrict__ v1,
                     const float* __restrict__ g2, const float* __restrict__ b2,
                     const float* __restrict__ m2, const float* __restrict__ v2,
                     const float* __restrict__ g3, const float* __restrict__ b3,
                     const float* __restrict__ m3, const float* __restrict__ v3,
                     unsigned short* __restrict__ wpb, unsigned short* __restrict__ w2b,
                     unsigned short* __restrict__ w3b, unsigned short* __restrict__ w1b,
                     float* __restrict__ c1s, float* __restrict__ c2s,
                     float* __restrict__ c3s)
{
    int t = blockIdx.x * 256 + threadIdx.x;
    if (t < 9216) {
        int oc = t / 288, k = t % 288;
        int n = k >> 5, ic = k & 31;
        wpb[t] = (oc < 18) ? f2bf(wp[oc * 288 + ic * 9 + n]) : (unsigned short)0;
    } else if (t < 18432) {
        int i = t - 9216;
        int oc = i / 288, k = i % 288;
        int n = k >> 5, ic = k & 31;
        float inv = g2[oc] * rsqrtf(v2[oc] + 1e-5f);
        w2b[i] = f2bf(w2[oc * 288 + ic * 9 + n] * inv);
    } else if (t < 36864) {
        int i = t - 18432;
        int oc = i / 288, k = i % 288;
        int n = k >> 5, ic = k & 31;
        float inv = g3[oc] * rsqrtf(v3[oc] + 1e-5f);
        w3b[i] = f2bf(w3[oc * 288 + ic * 9 + n] * inv);
    } else if (t < 37888) {
        int i = t - 36864;        // i = oc*32 + k, k = n*3+ic
        int oc = i >> 5, k = i & 31;
        int n = k / 3, ic = k - n * 3;
        float inv = g1[oc] * rsqrtf(v1[oc] + 1e-5f);
        w1b[i] = (k < 27) ? f2bf(w1[oc * 27 + ic * 9 + n] * inv) : (unsigned short)0;
    } else if (t < 37920) {
        int c = t - 37888;        // 0..31
        float inv = g1[c] * rsqrtf(v1[c] + 1e-5f);
        c1s[c] = b1[c] - m1[c] * inv;
    } else if (t < 37952) {
        int c = t - 37920;
        float inv = g2[c] * rsqrtf(v2[c] + 1e-5f);
        c2s[c] = b2[c] - m2[c] * inv;
    } else if (t < 38016) {
        int c = t - 37952;        // 0..63
        float inv = g3[c] * rsqrtf(v3[c] + 1e-5f);
        c3s[c] = b3[c] - m3[c] * inv;
    }
}

// ======= mega-kernel: conv1 -> LDS img1 -> p_conv+bilinear+conv2 -> LDS img2 -> conv3+pool -> cls =======
__global__ __launch_bounds__(768, 3) void meganet(
    const float* __restrict__ x,
    const unsigned short* __restrict__ wpb, const unsigned short* __restrict__ w2b,
    const unsigned short* __restrict__ w3b, const unsigned short* __restrict__ w1b,
    const float* __restrict__ c1s, const float* __restrict__ c2s,
    const float* __restrict__ c3s, const float* __restrict__ bp,
    const float* __restrict__ wc, const float* __restrict__ bc,
    float* __restrict__ outp)
{
    __shared__ __align__(16) unsigned char ALL[L_TOT];
    int t = threadIdx.x, b = blockIdx.x;
    int w = t >> 6, l = t & 63, col = l & 15, q = l >> 4;

    unsigned char* img1 = ALL + L_IMG1;
    unsigned char* uimg = ALL + L_U;          // x staging then h2

    // ---- phase 0: stage x + weights into LDS (all coalesced) ----
    {
        const float4* xg = (const float4*)(x + (size_t)b * 2352);
        float4* xl = (float4*)uimg;
        for (int i = t; i < 588; i += 768) xl[i] = xg[i];
    }
    {
        const uint4* s1 = (const uint4*)wpb;
        const uint4* s2 = (const uint4*)w2b;
        for (int i = t; i < 2304; i += 768) {      // wp rows 0..31, w2 rows 32..63
            int row = i / 36, g = i - row * 36;
            uint4 v = (row < 32) ? s1[row * 36 + g] : s2[(row - 32) * 36 + g];
            *(uint4*)(ALL + L_WL + row * 592 + g * 16) = v;
        }
        if (t < 128) *(uint4*)(ALL + L_OFFT + t * 16) = ((const uint4*)w1b)[t];
    }
    if (t == 700) ((float*)uimg)[2352] = 0.f;                       // conv1 zero slot
    if (t < 4)  *(uint4*)(img1 + 784 * 64 + t * 16) = make_uint4(0u, 0u, 0u, 0u);
    if (t >= 4 && t < 8) *(uint4*)(uimg + 784 * 64 + (t - 4) * 16) = make_uint4(0u, 0u, 0u, 0u);

    float s0 = c1s[col], s1v = c1s[16 + col];
    float bias0 = bp[col];
    float bias1 = (col < 2) ? bp[16 + col] : 0.f;
    float sh0 = c2s[col], sh1 = c2s[16 + col];

    __syncthreads();

    // ---- phase 1: conv1 (3->32, pad1, relu, bn-folded) -> img1 (swizzled) ----
    {
        short8 bf0 = *(const short8*)(ALL + L_OFFT + col * 64 + q * 16);
        short8 bf1 = *(const short8*)(ALL + L_OFFT + (16 + col) * 64 + q * 16);
        const float* xs = (const float*)uimg;
        for (int mt = w; mt < 49; mt += 12) {
            int p = mt * 16 + col;
            int y = p / 28, xx = p % 28;
            unsigned au[4];
#pragma unroll
            for (int jp = 0; jp < 4; jp++) {
                float vv[2];
#pragma unroll
                for (int h = 0; h < 2; h++) {
                    int k = q * 8 + jp * 2 + h;
                    int n = k / 3, ic = k - n * 3;
                    int yy = y + n / 3 - 1, xc = xx + n % 3 - 1;
                    bool ok = (k < 27) && ((unsigned)yy < 28u) && ((unsigned)xc < 28u);
                    int idx = ok ? (ic * 784 + yy * 28 + xc) : 2352;
                    vv[h] = xs[idx];
                }
                au[jp] = pk2bf(vv[0], vv[1]);
            }
            uint4 a4 = make_uint4(au[0], au[1], au[2], au[3]);
            short8 a = *(short8*)&a4;
            floatx4 d0 = {0.f, 0.f, 0.f, 0.f}, d1 = {0.f, 0.f, 0.f, 0.f};
            d0 = __builtin_amdgcn_mfma_f32_16x16x32_bf16(a, bf0, d0, 0, 0, 0);
            d1 = __builtin_amdgcn_mfma_f32_16x16x32_bf16(a, bf1, d1, 0, 0, 0);
#pragma unroll
            for (int r = 0; r < 4; r++) {
                int pout = mt * 16 + q * 4 + r;
                *(unsigned short*)(img1 + sw64ch(pout, col)) = f2bf(fmaxf(d0[r], 0.f) + s0);
                *(unsigned short*)(img1 + sw64ch(pout, 16 + col)) = f2bf(fmaxf(d1[r], 0.f) + s1v);
            }
        }
    }
    __syncthreads();

    // ---- phase 2: p_conv MFMA -> offsets -> bilinear -> conv2 MFMA -> uimg ----
    {
        const unsigned char* ib = img1;
        float* otw = (float*)(ALL + L_OFFT) + w * 288;

        for (int mt = w; mt < 49; mt += 12) {
            int p = mt * 16 + col;
            int y = p / 28, xx = p % 28;

            // p_conv for this 16-pixel tile (B from LDS pool rows 0..31)
            floatx4 a0 = {0.f, 0.f, 0.f, 0.f}, a1 = {0.f, 0.f, 0.f, 0.f};
#pragma unroll
            for (int n = 0; n < 9; n++) {
                int yy = y + n / 3 - 1, xc = xx + n % 3 - 1;
                bool ok = ((unsigned)yy < 28u) && ((unsigned)xc < 28u);
                int tp = ok ? (yy * 28 + xc) : 784;      // 784 = zero slot
                short8 a  = *(const short8*)(ib + sw64(tp, q));
                short8 p0 = *(const short8*)(ALL + L_WL + col * 592 + n * 64 + q * 16);
                short8 p1 = *(const short8*)(ALL + L_WL + (16 + col) * 592 + n * 64 + q * 16);
                a0 = __builtin_amdgcn_mfma_f32_16x16x32_bf16(a, p0, a0, 0, 0, 0);
                a1 = __builtin_amdgcn_mfma_f32_16x16x32_bf16(a, p1, a1, 0, 0, 0);
            }
#pragma unroll
            for (int r = 0; r < 4; r++)
                otw[(q * 4 + r) * 18 + col] = a0[r] + bias0;
            if (col < 2) {
#pragma unroll
                for (int r = 0; r < 4; r++)
                    otw[(q * 4 + r) * 18 + 16 + col] = a1[r] + bias1;
            }
            __asm__ volatile("s_waitcnt lgkmcnt(0)" ::: "memory");

            // bilinear A-frags + conv2 MFMA (B rows 32..63, scale-folded)
            floatx4 d0 = {0.f, 0.f, 0.f, 0.f}, d1 = {0.f, 0.f, 0.f, 0.f};
#pragma unroll
            for (int n = 0; n < 9; n++) {
                float offy = otw[col * 18 + n];
                float offx = otw[col * 18 + 9 + n];
                float py = (float)(y + n / 3) + offy;       // padded coords
                float px = (float)(xx + n % 3) + offx;
                float fy = floorf(py), fx = floorf(px);
                float qy0 = fminf(fmaxf(fy, 0.f), 29.f);
                float qy1 = fminf(fmaxf(fy + 1.f, 0.f), 29.f);
                float qx0 = fminf(fmaxf(fx, 0.f), 29.f);
                float qx1 = fminf(fmaxf(fx + 1.f, 0.f), 29.f);
                float pyc = fminf(fmaxf(py, 0.f), 29.f);
                float pxc = fminf(fmaxf(px, 0.f), 29.f);
                float glt = (1.f + (qy0 - pyc)) * (1.f + (qx0 - pxc));
                float grb = (1.f - (qy1 - pyc)) * (1.f - (qx1 - pxc));
                float glb = (1.f + (qy0 - pyc)) * (1.f - (qx1 - pxc));
                float grt = (1.f - (qy1 - pyc)) * (1.f + (qx0 - pxc));
                int iy0 = (int)qy0, iy1 = (int)qy1, ix0 = (int)qx0, ix1 = (int)qx1;
                int ly0 = iy0 - 1, ly1 = iy1 - 1, lx0 = ix0 - 1, lx1 = ix1 - 1;
                bool v00 = ((unsigned)ly0 < 28u) && ((unsigned)lx0 < 28u);
                bool v11 = ((unsigned)ly1 < 28u) && ((unsigned)lx1 < 28u);
                bool v01 = ((unsigned)ly0 < 28u) && ((unsigned)lx1 < 28u);
                bool v10 = ((unsigned)ly1 < 28u) && ((unsigned)lx0 < 28u);
                int p00 = v00 ? (ly0 * 28 + lx0) : 784;
                int p11 = v11 ? (ly1 * 28 + lx1) : 784;
                int p01 = v01 ? (ly0 * 28 + lx1) : 784;
                int p10 = v10 ? (ly1 * 28 + lx0) : 784;
                uint4 u00 = *(const uint4*)(ib + sw64(p00, q));
                uint4 u11 = *(const uint4*)(ib + sw64(p11, q));
                uint4 u01 = *(const uint4*)(ib + sw64(p01, q));
                uint4 u10 = *(const uint4*)(ib + sw64(p10, q));
                floatx2 f0 = up2(u00.x) * glt + up2(u11.x) * grb + up2(u01.x) * glb + up2(u10.x) * grt;
                floatx2 f1 = up2(u00.y) * glt + up2(u11.y) * grb + up2(u01.y) * glb + up2(u10.y) * grt;
                floatx2 f2 = up2(u00.z) * glt + up2(u11.z) * grb + up2(u01.z) * glb + up2(u10.z) * grt;
                floatx2 f3 = up2(u00.w) * glt + up2(u11.w) * grb + up2(u01.w) * glb + up2(u10.w) * grt;
                uint4 af4 = make_uint4(pk2bf(f0.x, f0.y), pk2bf(f1.x, f1.y),
                                       pk2bf(f2.x, f2.y), pk2bf(f3.x, f3.y));
                short8 af = *(short8*)&af4;
                short8 wb0 = *(const short8*)(ALL + L_WL + (32 + col) * 592 + n * 64 + q * 16);
                short8 wb1 = *(const short8*)(ALL + L_WL + (48 + col) * 592 + n * 64 + q * 16);
                d0 = __builtin_amdgcn_mfma_f32_16x16x32_bf16(af, wb0, d0, 0, 0, 0);
                d1 = __builtin_amdgcn_mfma_f32_16x16x32_bf16(af, wb1, d1, 0, 0, 0);
            }
            // relu + shift2 + store to LDS uimg (swizzled, 64B/px)
#pragma unroll
            for (int r = 0; r < 4; r++) {
                int pout = mt * 16 + q * 4 + r;
                *(unsigned short*)(uimg + sw64ch(pout, col)) = f2bf(fmaxf(d0[r], 0.f) + sh0);
                *(unsigned short*)(uimg + sw64ch(pout, 16 + col)) = f2bf(fmaxf(d1[r], 0.f) + sh1);
            }
        }
    }
    __syncthreads();

    // ---- phase 3: stage w3 (bf16, pre-scaled) -> pool rows 0..63 (coalesced) ----
    {
        const uint4* src = (const uint4*)w3b;
        for (int i = t; i < 2304; i += 768) {
            int row = i / 36, g = i - row * 36;
            *(uint4*)(ALL + L_WL + row * 592 + g * 16) = src[row * 36 + g];
        }
    }
    __syncthreads();

    // ---- phase 4: conv3 MFMA + relu + global-sum partials ----
    {
        float* part = (float*)(ALL + L_OFFT);   // [12][32]
        int ocp = w & 1;
        const unsigned char* ib = uimg;
        float psA = 0.f, psB = 0.f;
        for (int mt = (w >> 1); mt < 49; mt += 6) {
            int p = mt * 16 + col;
            int y = p / 28, xx = p % 28;
            floatx4 cA = {0.f, 0.f, 0.f, 0.f}, cB = {0.f, 0.f, 0.f, 0.f};
#pragma unroll
            for (int n = 0; n < 9; n++) {
                int yy = y + n / 3 - 1, xc = xx + n % 3 - 1;
                bool ok = ((unsigned)yy < 28u) && ((unsigned)xc < 28u);
                int tp = ok ? (yy * 28 + xc) : 784;
                short8 a  = *(const short8*)(ib + sw64(tp, q));
                short8 wA = *(const short8*)(ALL + L_WL + (ocp * 32 + col) * 592 + n * 64 + q * 16);
                short8 wB = *(const short8*)(ALL + L_WL + (ocp * 32 + 16 + col) * 592 + n * 64 + q * 16);
                cA = __builtin_amdgcn_mfma_f32_16x16x32_bf16(a, wA, cA, 0, 0, 0);
                cB = __builtin_amdgcn_mfma_f32_16x16x32_bf16(a, wB, cB, 0, 0, 0);
            }
            psA += fmaxf(cA[0], 0.f) + fmaxf(cA[1], 0.f) + fmaxf(cA[2], 0.f) + fmaxf(cA[3], 0.f);
            psB += fmaxf(cB[0], 0.f) + fmaxf(cB[1], 0.f) + fmaxf(cB[2], 0.f) + fmaxf(cB[3], 0.f);
        }
        psA += __shfl_xor(psA, 16, 64); psA += __shfl_xor(psA, 32, 64);
        psB += __shfl_xor(psB, 16, 64); psB += __shfl_xor(psB, 32, 64);
        if (l < 16) { part[w * 32 + l] = psA; part[w * 32 + 16 + l] = psB; }
    }
    __syncthreads();

    // ---- phase 5: classifier (one wave): shift3, mean, linear 64->10, log_softmax ----
    if (t < 64) {
        const float* part = (const float*)(ALL + L_OFFT);
        int hi = t >> 5, c = t & 31;
        float s = 0.f;
#pragma unroll
        for (int j = 0; j < 6; j++) s += part[(2 * j + hi) * 32 + c];   // oc = t
        float feat = s * (1.f / 784.f) + c3s[t];
        float lg[10];
        float mx = -1e30f;
#pragma unroll
        for (int j = 0; j < 10; j++) {
            float v = feat * wc[j * 64 + t];
            v += __shfl_xor(v, 1, 64);  v += __shfl_xor(v, 2, 64);
            v += __shfl_xor(v, 4, 64);  v += __shfl_xor(v, 8, 64);
            v += __shfl_xor(v, 16, 64); v += __shfl_xor(v, 32, 64);
            lg[j] = v + bc[j];
            mx = fmaxf(mx, lg[j]);
        }
        float se = 0.f;
#pragma unroll
        for (int j = 0; j < 10; j++) se += expf(lg[j] - mx);
        float lse = logf(se);
#pragma unroll
        for (int j = 0; j < 10; j++)
            if (t == j) outp[(size_t)b * 10 + j] = lg[j] - mx - lse;
    }
}

extern "C" void kernel_launch(void* const* d_in, const int* in_sizes, int n_in,
                              void* d_out, int out_size, void* d_ws, size_t ws_size,
                              hipStream_t stream)
{
    (void)in_sizes; (void)n_in; (void)out_size; (void)ws_size;
    const float* x  = (const float*)d_in[0];
    const float* w1 = (const float*)d_in[1];
    const float* g1 = (const float*)d_in[2];
    const float* b1 = (const float*)d_in[3];
    const float* m1 = (const float*)d_in[4];
    const float* v1 = (const float*)d_in[5];
    const float* wp = (const float*)d_in[6];
    const float* bp = (const float*)d_in[7];
    const float* w2 = (const float*)d_in[8];
    const float* g2 = (const float*)d_in[9];
    const float* b2 = (const float*)d_in[10];
    const float* m2 = (const float*)d_in[11];
    const float* v2 = (const float*)d_in[12];
    const float* w3 = (const float*)d_in[13];
    const float* g3 = (const float*)d_in[14];
    const float* b3 = (const float*)d_in[15];
    const float* m3 = (const float*)d_in[16];
    const float* v3 = (const float*)d_in[17];
    const float* wc = (const float*)d_in[18];
    const float* bc = (const float*)d_in[19];
    float* outp = (float*)d_out;

    unsigned char* ws = (unsigned char*)d_ws;
    unsigned short* wpb = (unsigned short*)(ws + WPB_OFF);
    unsigned short* w2b = (unsigned short*)(ws + W2B_OFF);
    unsigned short* w3b = (unsigned short*)(ws + W3B_OFF);
    unsigned short* w1b = (unsigned short*)(ws + W1B_OFF);
    float* c1s = (float*)(ws + C1S_OFF);
    float* c2s = (float*)(ws + C2S_OFF);
    float* c3s = (float*)(ws + C3S_OFF);

    wcvt<<<149, 256, 0, stream>>>(wp, w2, w3, w1, g1, b1, m1, v1,
                                  g2, b2, m2, v2, g3, b3, m3, v3,
                                  wpb, w2b, w3b, w1b, c1s, c2s, c3s);
    meganet<<<NB, 768, 0, stream>>>(x, wpb, w2b, w3b, w1b, c1s, c2s, c3s,
                                    bp, wc, bc, outp);
}

// Round 13
// 138.022 us; speedup vs baseline: 1.0319x; 1.0319x over previous
//
#include <hip/hip_runtime.h>
#include <hip/hip_bf16.h>
#include <math.h>

typedef __attribute__((ext_vector_type(8))) short short8;   // 8 bf16 = 4 VGPRs (MFMA A/B frag)
typedef __attribute__((ext_vector_type(4))) float floatx4;  // MFMA C/D frag
typedef __attribute__((ext_vector_type(2))) float floatx2;

#define NB 256

// ---------------- workspace layout (bytes) ----------------
#define WPB_OFF 0u        // 32*288 bf16 [oc][k=n*32+ic], rows>=18 zero (p_conv, unscaled)
#define W2B_OFF 18432u    // 32*288 bf16, scaled by inv2[oc]
#define W3B_OFF 36864u    // 64*288 bf16, scaled by inv3[oc]
#define W1B_OFF 73728u    // 32*32 bf16 [oc][k=n*3+ic], k>=27 zero, scaled by inv1[oc]
#define C1S_OFF 75776u    // 32 f32 shift1
#define C2S_OFF 75904u    // 32 f32 shift2
#define C3S_OFF 76032u    // 64 f32 shift3

// ---------------- LDS layout (bytes) ----------------
#define L_IMG1 0            // 785*64 = 50240  (h1: 784 px + zero slot)
#define L_U    50240        // 785*64 = 50240  (x staging, then h2 interior + zero slot)
#define L_OFFT 100480       // w1 stash (2KB), then per-wave offsets [16][288]f32 (18432B), then part[16][32]
#define L_WL   118912       // 64 rows * 592 B (wp+w2 rows, later w3 rows)
#define L_TOT  156800

static __device__ __forceinline__ unsigned short f2bf(float f) {
    unsigned u = __float_as_uint(f);
    u = (u + 0x7fffu + ((u >> 16) & 1u)) >> 16;   // RNE
    return (unsigned short)u;
}

static __device__ __forceinline__ unsigned pk2bf(float a, float b) {
    __hip_bfloat162 h = __float22bfloat162_rn(make_float2(a, b));
    unsigned r;
    __builtin_memcpy(&r, &h, 4);
    return r;
}

static __device__ __forceinline__ floatx2 up2(unsigned u) {
    floatx2 r;
    r.x = __uint_as_float(u << 16);
    r.y = __uint_as_float(u & 0xffff0000u);
    return r;
}

// ------- weight prep: bf16, pre-transposed, BN-scale-folded -------
__global__ void wcvt(const float* __restrict__ wp, const float* __restrict__ w2,
                     const float* __restrict__ w3, const float* __restrict__ w1,
                     const float* __restrict__ g1, const float* __restrict__ b1,
                     const float* __restrict__ m1, const float* __restrict__ v1,
                     const float* __restrict__ g2, const float* __restrict__ b2,
                     const float* __restrict__ m2, const float* __restrict__ v2,
                     const float* __restrict__ g3, const float* __restrict__ b3,
                     const float* __restrict__ m3, const float* __restrict__ v3,
                     unsigned short* __restrict__ wpb, unsigned short* __restrict__ w2b,
                     unsigned short* __restrict__ w3b, unsigned short* __restrict__ w1b,
                     float* __restrict__ c1s, float* __restrict__ c2s,
                     float* __restrict__ c3s)
{
    int t = blockIdx.x * 256 + threadIdx.x;
    if (t < 9216) {
        int oc = t / 288, k = t % 288;
        int n = k >> 5, ic = k & 31;
        wpb[t] = (oc < 18) ? f2bf(wp[oc * 288 + ic * 9 + n]) : (unsigned short)0;
    } else if (t < 18432) {
        int i = t - 9216;
        int oc = i / 288, k = i % 288;
        int n = k >> 5, ic = k & 31;
        float inv = g2[oc] * rsqrtf(v2[oc] + 1e-5f);
        w2b[i] = f2bf(w2[oc * 288 + ic * 9 + n] * inv);
    } else if (t < 36864) {
        int i = t - 18432;
        int oc = i / 288, k = i % 288;
        int n = k >> 5, ic = k & 31;
        float inv = g3[oc] * rsqrtf(v3[oc] + 1e-5f);
        w3b[i] = f2bf(w3[oc * 288 + ic * 9 + n] * inv);
    } else if (t < 37888) {
        int i = t - 36864;        // i = oc*32 + k, k = n*3+ic
        int oc = i >> 5, k = i & 31;
        int n = k / 3, ic = k - n * 3;
        float inv = g1[oc] * rsqrtf(v1[oc] + 1e-5f);
        w1b[i] = (k < 27) ? f2bf(w1[oc * 27 + ic * 9 + n] * inv) : (unsigned short)0;
    } else if (t < 37920) {
        int c = t - 37888;        // 0..31
        float inv = g1[c] * rsqrtf(v1[c] + 1e-5f);
        c1s[c] = b1[c] - m1[c] * inv;
    } else if (t < 37952) {
        int c = t - 37920;
        float inv = g2[c] * rsqrtf(v2[c] + 1e-5f);
        c2s[c] = b2[c] - m2[c] * inv;
    } else if (t < 38016) {
        int c = t - 37952;        // 0..63
        float inv = g3[c] * rsqrtf(v3[c] + 1e-5f);
        c3s[c] = b3[c] - m3[c] * inv;
    }
}

// ======= mega-kernel (16 waves): conv1 -> img1 -> p_conv+bilinear+conv2 -> uimg -> conv3+pool -> cls =======
__global__ __launch_bounds__(1024, 4) void meganet(
    const float* __restrict__ x,
    const unsigned short* __restrict__ wpb, const unsigned short* __restrict__ w2b,
    const unsigned short* __restrict__ w3b, const unsigned short* __restrict__ w1b,
    const float* __restrict__ c1s, const float* __restrict__ c2s,
    const float* __restrict__ c3s, const float* __restrict__ bp,
    const float* __restrict__ wc, const float* __restrict__ bc,
    float* __restrict__ outp)
{
    __shared__ __align__(16) unsigned char ALL[L_TOT];
    int t = threadIdx.x, b = blockIdx.x;
    int w = t >> 6, l = t & 63, col = l & 15, q = l >> 4;

    unsigned char* img1 = ALL + L_IMG1;
    unsigned char* uimg = ALL + L_U;          // x staging then h2

    // ---- phase 0: stage x + weights into LDS (all coalesced) ----
    {
        const float4* xg = (const float4*)(x + (size_t)b * 2352);
        float4* xl = (float4*)uimg;
        for (int i = t; i < 588; i += 1024) xl[i] = xg[i];
    }
    {
        const uint4* s1 = (const uint4*)wpb;
        const uint4* s2 = (const uint4*)w2b;
        for (int i = t; i < 2304; i += 1024) {     // wp rows 0..31, w2 rows 32..63
            int row = i / 36, g = i - row * 36;
            uint4 v = (row < 32) ? s1[row * 36 + g] : s2[(row - 32) * 36 + g];
            *(uint4*)(ALL + L_WL + row * 592 + g * 16) = v;
        }
        if (t < 128) *(uint4*)(ALL + L_OFFT + t * 16) = ((const uint4*)w1b)[t];
    }
    if (t == 1000) ((float*)uimg)[2352] = 0.f;                      // conv1 zero slot
    if (t < 4)  *(uint4*)(img1 + 784 * 64 + t * 16) = make_uint4(0u, 0u, 0u, 0u);
    if (t >= 4 && t < 8) *(uint4*)(uimg + 784 * 64 + (t - 4) * 16) = make_uint4(0u, 0u, 0u, 0u);

    float s0 = c1s[col], s1v = c1s[16 + col];
    float bias0 = bp[col];
    float bias1 = (col < 2) ? bp[16 + col] : 0.f;
    float sh0 = c2s[col], sh1 = c2s[16 + col];

    __syncthreads();

    // ---- phase 1: conv1 (3->32, pad1, relu, bn-folded) -> img1 ----
    {
        short8 bf0 = *(const short8*)(ALL + L_OFFT + col * 64 + q * 16);
        short8 bf1 = *(const short8*)(ALL + L_OFFT + (16 + col) * 64 + q * 16);
        const float* xs = (const float*)uimg;
        for (int mt = w; mt < 49; mt += 16) {
            int p = mt * 16 + col;
            int y = p / 28, xx = p % 28;
            unsigned au[4];
#pragma unroll
            for (int jp = 0; jp < 4; jp++) {
                float vv[2];
#pragma unroll
                for (int h = 0; h < 2; h++) {
                    int k = q * 8 + jp * 2 + h;
                    int n = k / 3, ic = k - n * 3;
                    int yy = y + n / 3 - 1, xc = xx + n % 3 - 1;
                    bool ok = (k < 27) && ((unsigned)yy < 28u) && ((unsigned)xc < 28u);
                    int idx = ok ? (ic * 784 + yy * 28 + xc) : 2352;
                    vv[h] = xs[idx];
                }
                au[jp] = pk2bf(vv[0], vv[1]);
            }
            uint4 a4 = make_uint4(au[0], au[1], au[2], au[3]);
            short8 a = *(short8*)&a4;
            floatx4 d0 = {0.f, 0.f, 0.f, 0.f}, d1 = {0.f, 0.f, 0.f, 0.f};
            d0 = __builtin_amdgcn_mfma_f32_16x16x32_bf16(a, bf0, d0, 0, 0, 0);
            d1 = __builtin_amdgcn_mfma_f32_16x16x32_bf16(a, bf1, d1, 0, 0, 0);
#pragma unroll
            for (int r = 0; r < 4; r++) {
                int pout = mt * 16 + q * 4 + r;
                *(unsigned short*)(img1 + pout * 64 + col * 2) = f2bf(fmaxf(d0[r], 0.f) + s0);
                *(unsigned short*)(img1 + pout * 64 + 32 + col * 2) = f2bf(fmaxf(d1[r], 0.f) + s1v);
            }
        }
    }
    __syncthreads();

    // ---- phase 2: p_conv MFMA -> offsets -> bilinear -> conv2 MFMA -> uimg ----
    {
        const unsigned char* ib = img1;
        float* otw = (float*)(ALL + L_OFFT) + w * 288;

        for (int mt = w; mt < 49; mt += 16) {
            int p = mt * 16 + col;
            int y = p / 28, xx = p % 28;

            // p_conv for this 16-pixel tile (B from LDS pool rows 0..31)
            floatx4 a0 = {0.f, 0.f, 0.f, 0.f}, a1 = {0.f, 0.f, 0.f, 0.f};
#pragma unroll
            for (int n = 0; n < 9; n++) {
                int yy = y + n / 3 - 1, xc = xx + n % 3 - 1;
                bool ok = ((unsigned)yy < 28u) && ((unsigned)xc < 28u);
                int tp = ok ? (yy * 28 + xc) : 784;      // 784 = zero slot
                short8 a  = *(const short8*)(ib + tp * 64 + q * 16);
                short8 p0 = *(const short8*)(ALL + L_WL + col * 592 + n * 64 + q * 16);
                short8 p1 = *(const short8*)(ALL + L_WL + (16 + col) * 592 + n * 64 + q * 16);
                a0 = __builtin_amdgcn_mfma_f32_16x16x32_bf16(a, p0, a0, 0, 0, 0);
                a1 = __builtin_amdgcn_mfma_f32_16x16x32_bf16(a, p1, a1, 0, 0, 0);
            }
#pragma unroll
            for (int r = 0; r < 4; r++)
                otw[(q * 4 + r) * 18 + col] = a0[r] + bias0;
            if (col < 2) {
#pragma unroll
                for (int r = 0; r < 4; r++)
                    otw[(q * 4 + r) * 18 + 16 + col] = a1[r] + bias1;
            }
            __asm__ volatile("s_waitcnt lgkmcnt(0)" ::: "memory");

            // bilinear A-frags + conv2 MFMA (B rows 32..63, scale-folded)
            floatx4 d0 = {0.f, 0.f, 0.f, 0.f}, d1 = {0.f, 0.f, 0.f, 0.f};
#pragma unroll
            for (int n = 0; n < 9; n++) {
                float offy = otw[col * 18 + n];
                float offx = otw[col * 18 + 9 + n];
                float py = (float)(y + n / 3) + offy;       // padded coords
                float px = (float)(xx + n % 3) + offx;
                float fy = floorf(py), fx = floorf(px);
                float qy0 = fminf(fmaxf(fy, 0.f), 29.f);
                float qy1 = fminf(fmaxf(fy + 1.f, 0.f), 29.f);
                float qx0 = fminf(fmaxf(fx, 0.f), 29.f);
                float qx1 = fminf(fmaxf(fx + 1.f, 0.f), 29.f);
                float pyc = fminf(fmaxf(py, 0.f), 29.f);
                float pxc = fminf(fmaxf(px, 0.f), 29.f);
                float glt = (1.f + (qy0 - pyc)) * (1.f + (qx0 - pxc));
                float grb = (1.f - (qy1 - pyc)) * (1.f - (qx1 - pxc));
                float glb = (1.f + (qy0 - pyc)) * (1.f - (qx1 - pxc));
                float grt = (1.f - (qy1 - pyc)) * (1.f + (qx0 - pxc));
                int iy0 = (int)qy0, iy1 = (int)qy1, ix0 = (int)qx0, ix1 = (int)qx1;
                int ly0 = iy0 - 1, ly1 = iy1 - 1, lx0 = ix0 - 1, lx1 = ix1 - 1;
                bool v00 = ((unsigned)ly0 < 28u) && ((unsigned)lx0 < 28u);
                bool v11 = ((unsigned)ly1 < 28u) && ((unsigned)lx1 < 28u);
                bool v01 = ((unsigned)ly0 < 28u) && ((unsigned)lx1 < 28u);
                bool v10 = ((unsigned)ly1 < 28u) && ((unsigned)lx0 < 28u);
                int p00 = v00 ? (ly0 * 28 + lx0) : 784;
                int p11 = v11 ? (ly1 * 28 + lx1) : 784;
                int p01 = v01 ? (ly0 * 28 + lx1) : 784;
                int p10 = v10 ? (ly1 * 28 + lx0) : 784;
                uint4 u00 = *(const uint4*)(ib + p00 * 64 + q * 16);
                uint4 u11 = *(const uint4*)(ib + p11 * 64 + q * 16);
                uint4 u01 = *(const uint4*)(ib + p01 * 64 + q * 16);
                uint4 u10 = *(const uint4*)(ib + p10 * 64 + q * 16);
                floatx2 f0 = up2(u00.x) * glt + up2(u11.x) * grb + up2(u01.x) * glb + up2(u10.x) * grt;
                floatx2 f1 = up2(u00.y) * glt + up2(u11.y) * grb + up2(u01.y) * glb + up2(u10.y) * grt;
                floatx2 f2 = up2(u00.z) * glt + up2(u11.z) * grb + up2(u01.z) * glb + up2(u10.z) * grt;
                floatx2 f3 = up2(u00.w) * glt + up2(u11.w) * grb + up2(u01.w) * glb + up2(u10.w) * grt;
                uint4 af4 = make_uint4(pk2bf(f0.x, f0.y), pk2bf(f1.x, f1.y),
                                       pk2bf(f2.x, f2.y), pk2bf(f3.x, f3.y));
                short8 af = *(short8*)&af4;
                short8 wb0 = *(const short8*)(ALL + L_WL + (32 + col) * 592 + n * 64 + q * 16);
                short8 wb1 = *(const short8*)(ALL + L_WL + (48 + col) * 592 + n * 64 + q * 16);
                d0 = __builtin_amdgcn_mfma_f32_16x16x32_bf16(af, wb0, d0, 0, 0, 0);
                d1 = __builtin_amdgcn_mfma_f32_16x16x32_bf16(af, wb1, d1, 0, 0, 0);
            }
            // relu + shift2 + store to LDS uimg (interior layout, 64B/px)
#pragma unroll
            for (int r = 0; r < 4; r++) {
                int pout = mt * 16 + q * 4 + r;
                *(unsigned short*)(uimg + pout * 64 + col * 2) = f2bf(fmaxf(d0[r], 0.f) + sh0);
                *(unsigned short*)(uimg + pout * 64 + 32 + col * 2) = f2bf(fmaxf(d1[r], 0.f) + sh1);
            }
        }
    }
    __syncthreads();

    // ---- phase 3: stage w3 (bf16, pre-scaled) -> pool rows 0..63 (coalesced) ----
    {
        const uint4* src = (const uint4*)w3b;
        for (int i = t; i < 2304; i += 1024) {
            int row = i / 36, g = i - row * 36;
            *(uint4*)(ALL + L_WL + row * 592 + g * 16) = src[row * 36 + g];
        }
    }
    __syncthreads();

    // ---- phase 4: conv3 MFMA + relu + global-sum partials ----
    {
        float* part = (float*)(ALL + L_OFFT);   // [16][32]
        int ocp = w & 1;
        const unsigned char* ib = uimg;
        float psA = 0.f, psB = 0.f;
        for (int mt = (w >> 1); mt < 49; mt += 8) {
            int p = mt * 16 + col;
            int y = p / 28, xx = p % 28;
            floatx4 cA = {0.f, 0.f, 0.f, 0.f}, cB = {0.f, 0.f, 0.f, 0.f};
#pragma unroll
            for (int n = 0; n < 9; n++) {
                int yy = y + n / 3 - 1, xc = xx + n % 3 - 1;
                bool ok = ((unsigned)yy < 28u) && ((unsigned)xc < 28u);
                int tp = ok ? (yy * 28 + xc) : 784;
                short8 a  = *(const short8*)(ib + tp * 64 + q * 16);
                short8 wA = *(const short8*)(ALL + L_WL + (ocp * 32 + col) * 592 + n * 64 + q * 16);
                short8 wB = *(const short8*)(ALL + L_WL + (ocp * 32 + 16 + col) * 592 + n * 64 + q * 16);
                cA = __builtin_amdgcn_mfma_f32_16x16x32_bf16(a, wA, cA, 0, 0, 0);
                cB = __builtin_amdgcn_mfma_f32_16x16x32_bf16(a, wB, cB, 0, 0, 0);
            }
            psA += fmaxf(cA[0], 0.f) + fmaxf(cA[1], 0.f) + fmaxf(cA[2], 0.f) + fmaxf(cA[3], 0.f);
            psB += fmaxf(cB[0], 0.f) + fmaxf(cB[1], 0.f) + fmaxf(cB[2], 0.f) + fmaxf(cB[3], 0.f);
        }
        psA += __shfl_xor(psA, 16, 64); psA += __shfl_xor(psA, 32, 64);
        psB += __shfl_xor(psB, 16, 64); psB += __shfl_xor(psB, 32, 64);
        if (l < 16) { part[w * 32 + l] = psA; part[w * 32 + 16 + l] = psB; }
    }
    __syncthreads();

    // ---- phase 5: classifier (one wave): shift3, mean, linear 64->10, log_softmax ----
    if (t < 64) {
        const float* part = (const float*)(ALL + L_OFFT);
        int hi = t >> 5, c = t & 31;
        float s = 0.f;
#pragma unroll
        for (int j = 0; j < 8; j++) s += part[(2 * j + hi) * 32 + c];   // oc = t
        float feat = s * (1.f / 784.f) + c3s[t];
        float lg[10];
        float mx = -1e30f;
#pragma unroll
        for (int j = 0; j < 10; j++) {
            float v = feat * wc[j * 64 + t];
            v += __shfl_xor(v, 1, 64);  v += __shfl_xor(v, 2, 64);
            v += __shfl_xor(v, 4, 64);  v += __shfl_xor(v, 8, 64);
            v += __shfl_xor(v, 16, 64); v += __shfl_xor(v, 32, 64);
            lg[j] = v + bc[j];
            mx = fmaxf(mx, lg[j]);
        }
        float se = 0.f;
#pragma unroll
        for (int j = 0; j < 10; j++) se += expf(lg[j] - mx);
        float lse = logf(se);
#pragma unroll
        for (int j = 0; j < 10; j++)
            if (t == j) outp[(size_t)b * 10 + j] = lg[j] - mx - lse;
    }
}

extern "C" void kernel_launch(void* const* d_in, const int* in_sizes, int n_in,
                              void* d_out, int out_size, void* d_ws, size_t ws_size,
                              hipStream_t stream)
{
    (void)in_sizes; (void)n_in; (void)out_size; (void)ws_size;
    const float* x  = (const float*)d_in[0];
    const float* w1 = (const float*)d_in[1];
    const float* g1 = (const float*)d_in[2];
    const float* b1 = (const float*)d_in[3];
    const float* m1 = (const float*)d_in[4];
    const float* v1 = (const float*)d_in[5];
    const float* wp = (const float*)d_in[6];
    const float* bp = (const float*)d_in[7];
    const float* w2 = (const float*)d_in[8];
    const float* g2 = (const float*)d_in[9];
    const float* b2 = (const float*)d_in[10];
    const float* m2 = (const float*)d_in[11];
    const float* v2 = (const float*)d_in[12];
    const float* w3 = (const float*)d_in[13];
    const float* g3 = (const float*)d_in[14];
    const float* b3 = (const float*)d_in[15];
    const float* m3 = (const float*)d_in[16];
    const float* v3 = (const float*)d_in[17];
    const float* wc = (const float*)d_in[18];
    const float* bc = (const float*)d_in[19];
    float* outp = (float*)d_out;

    unsigned char* ws = (unsigned char*)d_ws;
    unsigned short* wpb = (unsigned short*)(ws + WPB_OFF);
    unsigned short* w2b = (unsigned short*)(ws + W2B_OFF);
    unsigned short* w3b = (unsigned short*)(ws + W3B_OFF);
    unsigned short* w1b = (unsigned short*)(ws + W1B_OFF);
    float* c1s = (float*)(ws + C1S_OFF);
    float* c2s = (float*)(ws + C2S_OFF);
    float* c3s = (float*)(ws + C3S_OFF);

    wcvt<<<149, 256, 0, stream>>>(wp, w2, w3, w1, g1, b1, m1, v1,
                                  g2, b2, m2, v2, g3, b3, m3, v3,
                                  wpb, w2b, w3b, w1b, c1s, c2s, c3s);
    meganet<<<NB, 1024, 0, stream>>>(x, wpb, w2b, w3b, w1b, c1s, c2s, c3s,
                                     bp, wc, bc, outp);
}

// Round 14
// 134.201 us; speedup vs baseline: 1.0612x; 1.0285x over previous
//
#include <hip/hip_runtime.h>
#include <hip/hip_bf16.h>
#include <math.h>

typedef __attribute__((ext_vector_type(8))) short short8;   // 8 bf16 = 4 VGPRs (MFMA A/B frag)
typedef __attribute__((ext_vector_type(4))) float floatx4;  // MFMA C/D frag
typedef __attribute__((ext_vector_type(2))) float floatx2;

#define NB 256

// ---------------- workspace layout (bytes) ----------------
#define WPB_OFF 0u        // 32*288 bf16 [oc][k=n*32+ic], rows>=18 zero (p_conv, unscaled)
#define W2B_OFF 18432u    // 32*288 bf16, scaled by inv2[oc]
#define W3B_OFF 36864u    // 64*288 bf16, scaled by inv3[oc]
#define W1B_OFF 73728u    // 32*32 bf16 [oc][k=n*3+ic], k>=27 zero, scaled by inv1[oc]
#define C1S_OFF 75776u    // 32 f32 shift1
#define C2S_OFF 75904u    // 32 f32 shift2
#define C3S_OFF 76032u    // 64 f32 shift3

// ---------------- LDS layout (bytes) ----------------
#define L_IMG1 0            // 785*64 = 50240  (h1: 784 px + zero slot)
#define L_U    50240        // 785*64 = 50240  (x staging, then h2 interior + zero slot)
#define L_OFFT 100480       // 12 waves * 2048: [0,1152) raw offsets, [1152,1920) g/idx records
                            //   (w1 stash 2048B overlaps wave0 in phase 1; part[12][32] in phase 4)
#define L_WL   125056       // 64 rows * 592 B (wp+w2 rows, later w3 rows)
#define L_TOT  162944

static __device__ __forceinline__ unsigned short f2bf(float f) {
    unsigned u = __float_as_uint(f);
    u = (u + 0x7fffu + ((u >> 16) & 1u)) >> 16;   // RNE
    return (unsigned short)u;
}

static __device__ __forceinline__ unsigned pk2bf(float a, float b) {
    __hip_bfloat162 h = __float22bfloat162_rn(make_float2(a, b));
    unsigned r;
    __builtin_memcpy(&r, &h, 4);
    return r;
}

static __device__ __forceinline__ floatx2 up2(unsigned u) {
    floatx2 r;
    r.x = __uint_as_float(u << 16);
    r.y = __uint_as_float(u & 0xffff0000u);
    return r;
}

// pack two f32 -> packed f16 pair (plain IEEE conversions)
static __device__ __forceinline__ unsigned pkh(float a, float b) {
    _Float16 ha = (_Float16)a, hb = (_Float16)b;
    unsigned short ua, ub;
    __builtin_memcpy(&ua, &ha, 2);
    __builtin_memcpy(&ub, &hb, 2);
    return (unsigned)ua | ((unsigned)ub << 16);
}
static __device__ __forceinline__ floatx2 uph(unsigned u) {
    unsigned short lo = (unsigned short)(u & 0xffffu), hi = (unsigned short)(u >> 16);
    _Float16 hl, hh;
    __builtin_memcpy(&hl, &lo, 2);
    __builtin_memcpy(&hh, &hi, 2);
    floatx2 r; r.x = (float)hl; r.y = (float)hh;
    return r;
}

// ------- weight prep: bf16, pre-transposed, BN-scale-folded -------
__global__ void wcvt(const float* __restrict__ wp, const float* __restrict__ w2,
                     const float* __restrict__ w3, const float* __restrict__ w1,
                     const float* __restrict__ g1, const float* __restrict__ b1,
                     const float* __restrict__ m1, const float* __restrict__ v1,
                     const float* __restrict__ g2, const float* __restrict__ b2,
                     const float* __restrict__ m2, const float* __restrict__ v2,
                     const float* __restrict__ g3, const float* __restrict__ b3,
                     const float* __restrict__ m3, const float* __restrict__ v3,
                     unsigned short* __restrict__ wpb, unsigned short* __restrict__ w2b,
                     unsigned short* __restrict__ w3b, unsigned short* __restrict__ w1b,
                     float* __restrict__ c1s, float* __restrict__ c2s,
                     float* __restrict__ c3s)
{
    int t = blockIdx.x * 256 + threadIdx.x;
    if (t < 9216) {
        int oc = t / 288, k = t % 288;
        int n = k >> 5, ic = k & 31;
        wpb[t] = (oc < 18) ? f2bf(wp[oc * 288 + ic * 9 + n]) : (unsigned short)0;
    } else if (t < 18432) {
        int i = t - 9216;
        int oc = i / 288, k = i % 288;
        int n = k >> 5, ic = k & 31;
        float inv = g2[oc] * rsqrtf(v2[oc] + 1e-5f);
        w2b[i] = f2bf(w2[oc * 288 + ic * 9 + n] * inv);
    } else if (t < 36864) {
        int i = t - 18432;
        int oc = i / 288, k = i % 288;
        int n = k >> 5, ic = k & 31;
        float inv = g3[oc] * rsqrtf(v3[oc] + 1e-5f);
        w3b[i] = f2bf(w3[oc * 288 + ic * 9 + n] * inv);
    } else if (t < 37888) {
        int i = t - 36864;        // i = oc*32 + k, k = n*3+ic
        int oc = i >> 5, k = i & 31;
        int n = k / 3, ic = k - n * 3;
        float inv = g1[oc] * rsqrtf(v1[oc] + 1e-5f);
        w1b[i] = (k < 27) ? f2bf(w1[oc * 27 + ic * 9 + n] * inv) : (unsigned short)0;
    } else if (t < 37920) {
        int c = t - 37888;        // 0..31
        float inv = g1[c] * rsqrtf(v1[c] + 1e-5f);
        c1s[c] = b1[c] - m1[c] * inv;
    } else if (t < 37952) {
        int c = t - 37920;
        float inv = g2[c] * rsqrtf(v2[c] + 1e-5f);
        c2s[c] = b2[c] - m2[c] * inv;
    } else if (t < 38016) {
        int c = t - 37952;        // 0..63
        float inv = g3[c] * rsqrtf(v3[c] + 1e-5f);
        c3s[c] = b3[c] - m3[c] * inv;
    }
}

// ======= mega-kernel (12 waves): conv1 -> img1 -> p_conv+bilinear+conv2 -> uimg -> conv3+pool -> cls =======
__global__ __launch_bounds__(768, 3) void meganet(
    const float* __restrict__ x,
    const unsigned short* __restrict__ wpb, const unsigned short* __restrict__ w2b,
    const unsigned short* __restrict__ w3b, const unsigned short* __restrict__ w1b,
    const float* __restrict__ c1s, const float* __restrict__ c2s,
    const float* __restrict__ c3s, const float* __restrict__ bp,
    const float* __restrict__ wc, const float* __restrict__ bc,
    float* __restrict__ outp)
{
    __shared__ __align__(16) unsigned char ALL[L_TOT];
    int t = threadIdx.x, b = blockIdx.x;
    int w = t >> 6, l = t & 63, col = l & 15, q = l >> 4;

    unsigned char* img1 = ALL + L_IMG1;
    unsigned char* uimg = ALL + L_U;          // x staging then h2

    // ---- phase 0: stage x + weights into LDS (all coalesced) ----
    {
        const float4* xg = (const float4*)(x + (size_t)b * 2352);
        float4* xl = (float4*)uimg;
        for (int i = t; i < 588; i += 768) xl[i] = xg[i];
    }
    {
        const uint4* s1 = (const uint4*)wpb;
        const uint4* s2 = (const uint4*)w2b;
        for (int i = t; i < 2304; i += 768) {      // wp rows 0..31, w2 rows 32..63
            int row = i / 36, g = i - row * 36;
            uint4 v = (row < 32) ? s1[row * 36 + g] : s2[(row - 32) * 36 + g];
            *(uint4*)(ALL + L_WL + row * 592 + g * 16) = v;
        }
        if (t < 128) *(uint4*)(ALL + L_OFFT + t * 16) = ((const uint4*)w1b)[t];
    }
    if (t == 700) ((float*)uimg)[2352] = 0.f;                       // conv1 zero slot
    if (t < 4)  *(uint4*)(img1 + 784 * 64 + t * 16) = make_uint4(0u, 0u, 0u, 0u);
    if (t >= 4 && t < 8) *(uint4*)(uimg + 784 * 64 + (t - 4) * 16) = make_uint4(0u, 0u, 0u, 0u);

    float s0 = c1s[col], s1v = c1s[16 + col];
    float bias0 = bp[col];
    float bias1 = (col < 2) ? bp[16 + col] : 0.f;
    float sh0 = c2s[col], sh1 = c2s[16 + col];

    __syncthreads();

    // ---- phase 1: conv1 (3->32, pad1, relu, bn-folded) -> img1 ----
    {
        short8 bf0 = *(const short8*)(ALL + L_OFFT + col * 64 + q * 16);
        short8 bf1 = *(const short8*)(ALL + L_OFFT + (16 + col) * 64 + q * 16);
        const float* xs = (const float*)uimg;
        for (int mt = w; mt < 49; mt += 12) {
            int p = mt * 16 + col;
            int y = p / 28, xx = p % 28;
            unsigned au[4];
#pragma unroll
            for (int jp = 0; jp < 4; jp++) {
                float vv[2];
#pragma unroll
                for (int h = 0; h < 2; h++) {
                    int k = q * 8 + jp * 2 + h;
                    int n = k / 3, ic = k - n * 3;
                    int yy = y + n / 3 - 1, xc = xx + n % 3 - 1;
                    bool ok = (k < 27) && ((unsigned)yy < 28u) && ((unsigned)xc < 28u);
                    int idx = ok ? (ic * 784 + yy * 28 + xc) : 2352;
                    vv[h] = xs[idx];
                }
                au[jp] = pk2bf(vv[0], vv[1]);
            }
            uint4 a4 = make_uint4(au[0], au[1], au[2], au[3]);
            short8 a = *(short8*)&a4;
            floatx4 d0 = {0.f, 0.f, 0.f, 0.f}, d1 = {0.f, 0.f, 0.f, 0.f};
            d0 = __builtin_amdgcn_mfma_f32_16x16x32_bf16(a, bf0, d0, 0, 0, 0);
            d1 = __builtin_amdgcn_mfma_f32_16x16x32_bf16(a, bf1, d1, 0, 0, 0);
#pragma unroll
            for (int r = 0; r < 4; r++) {
                int pout = mt * 16 + q * 4 + r;
                *(unsigned short*)(img1 + pout * 64 + col * 2) = f2bf(fmaxf(d0[r], 0.f) + s0);
                *(unsigned short*)(img1 + pout * 64 + 32 + col * 2) = f2bf(fmaxf(d1[r], 0.f) + s1v);
            }
        }
    }
    __syncthreads();

    // ---- phase 2: p_conv MFMA -> offsets -> per-combo precompute -> bilinear -> conv2 MFMA -> uimg ----
    {
        const unsigned char* ib = img1;
        unsigned char* wsc = ALL + L_OFFT + w * 2048;
        float* otw = (float*)wsc;                  // [16 px][18 ch] raw offsets
        unsigned char* gscr = wsc + 1152;          // 48 records x 16 B {gA,gB,idxA,idxB}

        for (int mt = w; mt < 49; mt += 12) {
            int p = mt * 16 + col;
            int y = p / 28, xx = p % 28;

            // p_conv for this 16-pixel tile (B from LDS pool rows 0..31)
            floatx4 a0 = {0.f, 0.f, 0.f, 0.f}, a1 = {0.f, 0.f, 0.f, 0.f};
#pragma unroll
            for (int n = 0; n < 9; n++) {
                int yy = y + n / 3 - 1, xc = xx + n % 3 - 1;
                bool ok = ((unsigned)yy < 28u) && ((unsigned)xc < 28u);
                int tp = ok ? (yy * 28 + xc) : 784;      // 784 = zero slot
                short8 a  = *(const short8*)(ib + tp * 64 + q * 16);
                short8 p0 = *(const short8*)(ALL + L_WL + col * 592 + n * 64 + q * 16);
                short8 p1 = *(const short8*)(ALL + L_WL + (16 + col) * 592 + n * 64 + q * 16);
                a0 = __builtin_amdgcn_mfma_f32_16x16x32_bf16(a, p0, a0, 0, 0, 0);
                a1 = __builtin_amdgcn_mfma_f32_16x16x32_bf16(a, p1, a1, 0, 0, 0);
            }
#pragma unroll
            for (int r = 0; r < 4; r++)
                otw[(q * 4 + r) * 18 + col] = a0[r] + bias0;
            if (col < 2) {
#pragma unroll
                for (int r = 0; r < 4; r++)
                    otw[(q * 4 + r) * 18 + 16 + col] = a1[r] + bias1;
            }
            __asm__ volatile("s_waitcnt lgkmcnt(0)" ::: "memory");

            floatx4 d0 = {0.f, 0.f, 0.f, 0.f}, d1 = {0.f, 0.f, 0.f, 0.f};
#pragma unroll
            for (int tg = 0; tg < 3; tg++) {
                // precompute: 48 combos (16 px x 3 taps), one per lane l<48
                if (l < 48) {
                    int px = l & 15, n = tg * 3 + (l >> 4);
                    int pg = mt * 16 + px;
                    int yg = pg / 28, xg = pg % 28;
                    float offy = otw[px * 18 + n];
                    float offx = otw[px * 18 + 9 + n];
                    float py = (float)(yg + n / 3) + offy;       // padded coords
                    float pxf = (float)(xg + n % 3) + offx;
                    float fy = floorf(py), fx = floorf(pxf);
                    float qy0 = fminf(fmaxf(fy, 0.f), 29.f);
                    float qy1 = fminf(fmaxf(fy + 1.f, 0.f), 29.f);
                    float qx0 = fminf(fmaxf(fx, 0.f), 29.f);
                    float qx1 = fminf(fmaxf(fx + 1.f, 0.f), 29.f);
                    float pyc = fminf(fmaxf(py, 0.f), 29.f);
                    float pxc = fminf(fmaxf(pxf, 0.f), 29.f);
                    float glt = (1.f + (qy0 - pyc)) * (1.f + (qx0 - pxc));
                    float grb = (1.f - (qy1 - pyc)) * (1.f - (qx1 - pxc));
                    float glb = (1.f + (qy0 - pyc)) * (1.f - (qx1 - pxc));
                    float grt = (1.f - (qy1 - pyc)) * (1.f + (qx0 - pxc));
                    int iy0 = (int)qy0, iy1 = (int)qy1, ix0 = (int)qx0, ix1 = (int)qx1;
                    int ly0 = iy0 - 1, ly1 = iy1 - 1, lx0 = ix0 - 1, lx1 = ix1 - 1;
                    bool v00 = ((unsigned)ly0 < 28u) && ((unsigned)lx0 < 28u);
                    bool v11 = ((unsigned)ly1 < 28u) && ((unsigned)lx1 < 28u);
                    bool v01 = ((unsigned)ly0 < 28u) && ((unsigned)lx1 < 28u);
                    bool v10 = ((unsigned)ly1 < 28u) && ((unsigned)lx0 < 28u);
                    unsigned p00 = v00 ? (unsigned)(ly0 * 28 + lx0) : 784u;
                    unsigned p11 = v11 ? (unsigned)(ly1 * 28 + lx1) : 784u;
                    unsigned p01 = v01 ? (unsigned)(ly0 * 28 + lx1) : 784u;
                    unsigned p10 = v10 ? (unsigned)(ly1 * 28 + lx0) : 784u;
                    uint4 rec = make_uint4(pkh(glt, grb), pkh(glb, grt),
                                           p00 | (p11 << 16), p01 | (p10 << 16));
                    *(uint4*)(gscr + l * 16) = rec;
                }
                __asm__ volatile("s_waitcnt lgkmcnt(0)" ::: "memory");

                // consume: 3 taps, record broadcast across quads
#pragma unroll
                for (int k3 = 0; k3 < 3; k3++) {
                    int n = tg * 3 + k3;
                    uint4 rec = *(const uint4*)(gscr + (k3 * 16 + col) * 16);
                    floatx2 gA = uph(rec.x), gB = uph(rec.y);
                    float glt = gA.x, grb = gA.y, glb = gB.x, grt = gB.y;
                    int p00 = (int)(rec.z & 0xffffu), p11 = (int)(rec.z >> 16);
                    int p01 = (int)(rec.w & 0xffffu), p10 = (int)(rec.w >> 16);
                    uint4 u00 = *(const uint4*)(ib + p00 * 64 + q * 16);
                    uint4 u11 = *(const uint4*)(ib + p11 * 64 + q * 16);
                    uint4 u01 = *(const uint4*)(ib + p01 * 64 + q * 16);
                    uint4 u10 = *(const uint4*)(ib + p10 * 64 + q * 16);
                    floatx2 f0 = up2(u00.x) * glt + up2(u11.x) * grb + up2(u01.x) * glb + up2(u10.x) * grt;
                    floatx2 f1 = up2(u00.y) * glt + up2(u11.y) * grb + up2(u01.y) * glb + up2(u10.y) * grt;
                    floatx2 f2 = up2(u00.z) * glt + up2(u11.z) * grb + up2(u01.z) * glb + up2(u10.z) * grt;
                    floatx2 f3 = up2(u00.w) * glt + up2(u11.w) * grb + up2(u01.w) * glb + up2(u10.w) * grt;
                    uint4 af4 = make_uint4(pk2bf(f0.x, f0.y), pk2bf(f1.x, f1.y),
                                           pk2bf(f2.x, f2.y), pk2bf(f3.x, f3.y));
                    short8 af = *(short8*)&af4;
                    short8 wb0 = *(const short8*)(ALL + L_WL + (32 + col) * 592 + n * 64 + q * 16);
                    short8 wb1 = *(const short8*)(ALL + L_WL + (48 + col) * 592 + n * 64 + q * 16);
                    d0 = __builtin_amdgcn_mfma_f32_16x16x32_bf16(af, wb0, d0, 0, 0, 0);
                    d1 = __builtin_amdgcn_mfma_f32_16x16x32_bf16(af, wb1, d1, 0, 0, 0);
                }
            }
            // relu + shift2 + store to LDS uimg (interior layout, 64B/px)
#pragma unroll
            for (int r = 0; r < 4; r++) {
                int pout = mt * 16 + q * 4 + r;
                *(unsigned short*)(uimg + pout * 64 + col * 2) = f2bf(fmaxf(d0[r], 0.f) + sh0);
                *(unsigned short*)(uimg + pout * 64 + 32 + col * 2) = f2bf(fmaxf(d1[r], 0.f) + sh1);
            }
        }
    }
    __syncthreads();

    // ---- phase 3: stage w3 (bf16, pre-scaled) -> pool rows 0..63 (coalesced) ----
    {
        const uint4* src = (const uint4*)w3b;
        for (int i = t; i < 2304; i += 768) {
            int row = i / 36, g = i - row * 36;
            *(uint4*)(ALL + L_WL + row * 592 + g * 16) = src[row * 36 + g];
        }
    }
    __syncthreads();

    // ---- phase 4: conv3 MFMA + relu + global-sum partials ----
    {
        float* part = (float*)(ALL + L_OFFT);   // [12][32]
        int ocp = w & 1;
        const unsigned char* ib = uimg;
        float psA = 0.f, psB = 0.f;
        for (int mt = (w >> 1); mt < 49; mt += 6) {
            int p = mt * 16 + col;
            int y = p / 28, xx = p % 28;
            floatx4 cA = {0.f, 0.f, 0.f, 0.f}, cB = {0.f, 0.f, 0.f, 0.f};
#pragma unroll
            for (int n = 0; n < 9; n++) {
                int yy = y + n / 3 - 1, xc = xx + n % 3 - 1;
                bool ok = ((unsigned)yy < 28u) && ((unsigned)xc < 28u);
                int tp = ok ? (yy * 28 + xc) : 784;
                short8 a  = *(const short8*)(ib + tp * 64 + q * 16);
                short8 wA = *(const short8*)(ALL + L_WL + (ocp * 32 + col) * 592 + n * 64 + q * 16);
                short8 wB = *(const short8*)(ALL + L_WL + (ocp * 32 + 16 + col) * 592 + n * 64 + q * 16);
                cA = __builtin_amdgcn_mfma_f32_16x16x32_bf16(a, wA, cA, 0, 0, 0);
                cB = __builtin_amdgcn_mfma_f32_16x16x32_bf16(a, wB, cB, 0, 0, 0);
            }
            psA += fmaxf(cA[0], 0.f) + fmaxf(cA[1], 0.f) + fmaxf(cA[2], 0.f) + fmaxf(cA[3], 0.f);
            psB += fmaxf(cB[0], 0.f) + fmaxf(cB[1], 0.f) + fmaxf(cB[2], 0.f) + fmaxf(cB[3], 0.f);
        }
        psA += __shfl_xor(psA, 16, 64); psA += __shfl_xor(psA, 32, 64);
        psB += __shfl_xor(psB, 16, 64); psB += __shfl_xor(psB, 32, 64);
        if (l < 16) { part[w * 32 + l] = psA; part[w * 32 + 16 + l] = psB; }
    }
    __syncthreads();

    // ---- phase 5: classifier (one wave): shift3, mean, linear 64->10, log_softmax ----
    if (t < 64) {
        const float* part = (const float*)(ALL + L_OFFT);
        int hi = t >> 5, c = t & 31;
        float s = 0.f;
#pragma unroll
        for (int j = 0; j < 6; j++) s += part[(2 * j + hi) * 32 + c];   // oc = t
        float feat = s * (1.f / 784.f) + c3s[t];
        float lg[10];
        float mx = -1e30f;
#pragma unroll
        for (int j = 0; j < 10; j++) {
            float v = feat * wc[j * 64 + t];
            v += __shfl_xor(v, 1, 64);  v += __shfl_xor(v, 2, 64);
            v += __shfl_xor(v, 4, 64);  v += __shfl_xor(v, 8, 64);
            v += __shfl_xor(v, 16, 64); v += __shfl_xor(v, 32, 64);
            lg[j] = v + bc[j];
            mx = fmaxf(mx, lg[j]);
        }
        float se = 0.f;
#pragma unroll
        for (int j = 0; j < 10; j++) se += expf(lg[j] - mx);
        float lse = logf(se);
#pragma unroll
        for (int j = 0; j < 10; j++)
            if (t == j) outp[(size_t)b * 10 + j] = lg[j] - mx - lse;
    }
}

extern "C" void kernel_launch(void* const* d_in, const int* in_sizes, int n_in,
                              void* d_out, int out_size, void* d_ws, size_t ws_size,
                              hipStream_t stream)
{
    (void)in_sizes; (void)n_in; (void)out_size; (void)ws_size;
    const float* x  = (const float*)d_in[0];
    const float* w1 = (const float*)d_in[1];
    const float* g1 = (const float*)d_in[2];
    const float* b1 = (const float*)d_in[3];
    const float* m1 = (const float*)d_in[4];
    const float* v1 = (const float*)d_in[5];
    const float* wp = (const float*)d_in[6];
    const float* bp = (const float*)d_in[7];
    const float* w2 = (const float*)d_in[8];
    const float* g2 = (const float*)d_in[9];
    const float* b2 = (const float*)d_in[10];
    const float* m2 = (const float*)d_in[11];
    const float* v2 = (const float*)d_in[12];
    const float* w3 = (const float*)d_in[13];
    const float* g3 = (const float*)d_in[14];
    const float* b3 = (const float*)d_in[15];
    const float* m3 = (const float*)d_in[16];
    const float* v3 = (const float*)d_in[17];
    const float* wc = (const float*)d_in[18];
    const float* bc = (const float*)d_in[19];
    float* outp = (float*)d_out;

    unsigned char* ws = (unsigned char*)d_ws;
    unsigned short* wpb = (unsigned short*)(ws + WPB_OFF);
    unsigned short* w2b = (unsigned short*)(ws + W2B_OFF);
    unsigned short* w3b = (unsigned short*)(ws + W3B_OFF);
    unsigned short* w1b = (unsigned short*)(ws + W1B_OFF);
    float* c1s = (float*)(ws + C1S_OFF);
    float* c2s = (float*)(ws + C2S_OFF);
    float* c3s = (float*)(ws + C3S_OFF);

    wcvt<<<149, 256, 0, stream>>>(wp, w2, w3, w1, g1, b1, m1, v1,
                                  g2, b2, m2, v2, g3, b3, m3, v3,
                                  wpb, w2b, w3b, w1b, c1s, c2s, c3s);
    meganet<<<NB, 768, 0, stream>>>(x, wpb, w2b, w3b, w1b, c1s, c2s, c3s,
                                    bp, wc, bc, outp);
}

// Round 15
// 133.275 us; speedup vs baseline: 1.0686x; 1.0069x over previous
//
#include <hip/hip_runtime.h>
#include <hip/hip_bf16.h>
#include <math.h>

typedef __attribute__((ext_vector_type(8))) short short8;   // 8 bf16 = 4 VGPRs (MFMA A/B frag)
typedef __attribute__((ext_vector_type(4))) float floatx4;  // MFMA C/D frag
typedef __attribute__((ext_vector_type(2))) float floatx2;

#define NB 256

// ---------------- workspace layout (bytes) ----------------
#define WPB_OFF 0u        // 32*288 bf16 [oc][k=n*32+ic], rows>=18 zero (p_conv, unscaled)
#define W2B_OFF 18432u    // 32*288 bf16, scaled by inv2[oc]
#define W3B_OFF 36864u    // 64*288 bf16, scaled by inv3[oc]
#define W1B_OFF 73728u    // 32*32 bf16 [oc][k=n*3+ic], k>=27 zero, scaled by inv1[oc]
#define C1S_OFF 75776u    // 32 f32 shift1
#define C2S_OFF 75904u    // 32 f32 shift2
#define C3S_OFF 76032u    // 64 f32 shift3

// ---------------- LDS layout (bytes) ----------------
#define L_IMG1 0            // 785*64 = 50240  (h1: 784 px + zero slot)
#define L_U    50240        // 785*64 = 50240  (x staging, then h2 interior + zero slot)
#define L_OFFT 100480       // 12 waves * 2048: [0,1152) raw offsets, [1152,1920) g/idx records
#define L_WL   125056       // 64 rows * 592 B (wp+w2 rows, later w3 rows)
#define L_TOT  162944

static __device__ __forceinline__ unsigned short f2bf(float f) {
    unsigned u = __float_as_uint(f);
    u = (u + 0x7fffu + ((u >> 16) & 1u)) >> 16;   // RNE
    return (unsigned short)u;
}

static __device__ __forceinline__ unsigned pk2bf(float a, float b) {
    __hip_bfloat162 h = __float22bfloat162_rn(make_float2(a, b));
    unsigned r;
    __builtin_memcpy(&r, &h, 4);
    return r;
}

static __device__ __forceinline__ floatx2 up2(unsigned u) {
    floatx2 r;
    r.x = __uint_as_float(u << 16);
    r.y = __uint_as_float(u & 0xffff0000u);
    return r;
}

// pack two f32 -> packed f16 pair (plain IEEE conversions)
static __device__ __forceinline__ unsigned pkh(float a, float b) {
    _Float16 ha = (_Float16)a, hb = (_Float16)b;
    unsigned short ua, ub;
    __builtin_memcpy(&ua, &ha, 2);
    __builtin_memcpy(&ub, &hb, 2);
    return (unsigned)ua | ((unsigned)ub << 16);
}
static __device__ __forceinline__ floatx2 uph(unsigned u) {
    unsigned short lo = (unsigned short)(u & 0xffffu), hi = (unsigned short)(u >> 16);
    _Float16 hl, hh;
    __builtin_memcpy(&hl, &lo, 2);
    __builtin_memcpy(&hh, &hi, 2);
    floatx2 r; r.x = (float)hl; r.y = (float)hh;
    return r;
}

// ------- weight prep: bf16, pre-transposed, BN-scale-folded -------
__global__ void wcvt(const float* __restrict__ wp, const float* __restrict__ w2,
                     const float* __restrict__ w3, const float* __restrict__ w1,
                     const float* __restrict__ g1, const float* __restrict__ b1,
                     const float* __restrict__ m1, const float* __restrict__ v1,
                     const float* __restrict__ g2, const float* __restrict__ b2,
                     const float* __restrict__ m2, const float* __restrict__ v2,
                     const float* __restrict__ g3, const float* __restrict__ b3,
                     const float* __restrict__ m3, const float* __restrict__ v3,
                     unsigned short* __restrict__ wpb, unsigned short* __restrict__ w2b,
                     unsigned short* __restrict__ w3b, unsigned short* __restrict__ w1b,
                     float* __restrict__ c1s, float* __restrict__ c2s,
                     float* __restrict__ c3s)
{
    int t = blockIdx.x * 256 + threadIdx.x;
    if (t < 9216) {
        int oc = t / 288, k = t % 288;
        int n = k >> 5, ic = k & 31;
        wpb[t] = (oc < 18) ? f2bf(wp[oc * 288 + ic * 9 + n]) : (unsigned short)0;
    } else if (t < 18432) {
        int i = t - 9216;
        int oc = i / 288, k = i % 288;
        int n = k >> 5, ic = k & 31;
        float inv = g2[oc] * rsqrtf(v2[oc] + 1e-5f);
        w2b[i] = f2bf(w2[oc * 288 + ic * 9 + n] * inv);
    } else if (t < 36864) {
        int i = t - 18432;
        int oc = i / 288, k = i % 288;
        int n = k >> 5, ic = k & 31;
        float inv = g3[oc] * rsqrtf(v3[oc] + 1e-5f);
        w3b[i] = f2bf(w3[oc * 288 + ic * 9 + n] * inv);
    } else if (t < 37888) {
        int i = t - 36864;        // i = oc*32 + k, k = n*3+ic
        int oc = i >> 5, k = i & 31;
        int n = k / 3, ic = k - n * 3;
        float inv = g1[oc] * rsqrtf(v1[oc] + 1e-5f);
        w1b[i] = (k < 27) ? f2bf(w1[oc * 27 + ic * 9 + n] * inv) : (unsigned short)0;
    } else if (t < 37920) {
        int c = t - 37888;        // 0..31
        float inv = g1[c] * rsqrtf(v1[c] + 1e-5f);
        c1s[c] = b1[c] - m1[c] * inv;
    } else if (t < 37952) {
        int c = t - 37920;
        float inv = g2[c] * rsqrtf(v2[c] + 1e-5f);
        c2s[c] = b2[c] - m2[c] * inv;
    } else if (t < 38016) {
        int c = t - 37952;        // 0..63
        float inv = g3[c] * rsqrtf(v3[c] + 1e-5f);
        c3s[c] = b3[c] - m3[c] * inv;
    }
}

// ======= mega-kernel (12 waves): conv1 -> img1 -> p_conv+bilinear+conv2 -> uimg -> conv3+pool -> cls =======
__global__ __launch_bounds__(768, 3) void meganet(
    const float* __restrict__ x,
    const unsigned short* __restrict__ wpb, const unsigned short* __restrict__ w2b,
    const unsigned short* __restrict__ w3b, const unsigned short* __restrict__ w1b,
    const float* __restrict__ c1s, const float* __restrict__ c2s,
    const float* __restrict__ c3s, const float* __restrict__ bp,
    const float* __restrict__ wc, const float* __restrict__ bc,
    float* __restrict__ outp)
{
    __shared__ __align__(16) unsigned char ALL[L_TOT];
    int t = threadIdx.x, b = blockIdx.x;
    int w = t >> 6, l = t & 63, col = l & 15, q = l >> 4;

    unsigned char* img1 = ALL + L_IMG1;
    unsigned char* uimg = ALL + L_U;          // x staging then h2

    // ---- phase 0: stage x + weights into LDS (all coalesced) ----
    {
        const float4* xg = (const float4*)(x + (size_t)b * 2352);
        float4* xl = (float4*)uimg;
        for (int i = t; i < 588; i += 768) xl[i] = xg[i];
    }
    {
        const uint4* s1 = (const uint4*)wpb;
        const uint4* s2 = (const uint4*)w2b;
        for (int i = t; i < 2304; i += 768) {      // wp rows 0..31, w2 rows 32..63
            int row = i / 36, g = i - row * 36;
            uint4 v = (row < 32) ? s1[row * 36 + g] : s2[(row - 32) * 36 + g];
            *(uint4*)(ALL + L_WL + row * 592 + g * 16) = v;
        }
        if (t < 128) *(uint4*)(ALL + L_OFFT + t * 16) = ((const uint4*)w1b)[t];
    }
    if (t == 700) ((float*)uimg)[2352] = 0.f;                       // conv1 zero slot
    if (t < 4)  *(uint4*)(img1 + 784 * 64 + t * 16) = make_uint4(0u, 0u, 0u, 0u);
    if (t >= 4 && t < 8) *(uint4*)(uimg + 784 * 64 + (t - 4) * 16) = make_uint4(0u, 0u, 0u, 0u);

    float s0 = c1s[col], s1v = c1s[16 + col];
    float bias0 = bp[col];
    float bias1 = (col < 2) ? bp[16 + col] : 0.f;
    float sh0 = c2s[col], sh1 = c2s[16 + col];

    __syncthreads();

    // ---- phase 1: conv1 (3->32, pad1, relu, bn-folded) -> img1 ----
    {
        short8 bf0 = *(const short8*)(ALL + L_OFFT + col * 64 + q * 16);
        short8 bf1 = *(const short8*)(ALL + L_OFFT + (16 + col) * 64 + q * 16);
        const float* xs = (const float*)uimg;
        for (int mt = w; mt < 49; mt += 12) {
            int p = mt * 16 + col;
            int y = p / 28, xx = p % 28;
            unsigned au[4];
#pragma unroll
            for (int jp = 0; jp < 4; jp++) {
                float vv[2];
#pragma unroll
                for (int h = 0; h < 2; h++) {
                    int k = q * 8 + jp * 2 + h;
                    int n = k / 3, ic = k - n * 3;
                    int yy = y + n / 3 - 1, xc = xx + n % 3 - 1;
                    bool ok = (k < 27) && ((unsigned)yy < 28u) && ((unsigned)xc < 28u);
                    int idx = ok ? (ic * 784 + yy * 28 + xc) : 2352;
                    vv[h] = xs[idx];
                }
                au[jp] = pk2bf(vv[0], vv[1]);
            }
            uint4 a4 = make_uint4(au[0], au[1], au[2], au[3]);
            short8 a = *(short8*)&a4;
            floatx4 d0 = {0.f, 0.f, 0.f, 0.f}, d1 = {0.f, 0.f, 0.f, 0.f};
            d0 = __builtin_amdgcn_mfma_f32_16x16x32_bf16(a, bf0, d0, 0, 0, 0);
            d1 = __builtin_amdgcn_mfma_f32_16x16x32_bf16(a, bf1, d1, 0, 0, 0);
#pragma unroll
            for (int r = 0; r < 4; r++) {
                int pout = mt * 16 + q * 4 + r;
                *(unsigned short*)(img1 + pout * 64 + col * 2) = f2bf(fmaxf(d0[r], 0.f) + s0);
                *(unsigned short*)(img1 + pout * 64 + 32 + col * 2) = f2bf(fmaxf(d1[r], 0.f) + s1v);
            }
        }
    }
    __syncthreads();

    // ---- phase 2: p_conv MFMA -> offsets -> per-combo precompute -> bilinear -> conv2 MFMA -> uimg ----
    {
        const unsigned char* ib = img1;
        unsigned char* wsc = ALL + L_OFFT + w * 2048;
        float* otw = (float*)wsc;                  // [16 px][18 ch] raw offsets
        unsigned char* gscr = wsc + 1152;          // 48 records x 16 B {gA,gB,idxA,idxB}

        // hoist conv2 B-frags into registers (loop-invariant; 72 VGPRs, cap 170)
        short8 b2fr[18];
#pragma unroll
        for (int n = 0; n < 9; n++) {
            b2fr[n]     = *(const short8*)(ALL + L_WL + (32 + col) * 592 + n * 64 + q * 16);
            b2fr[9 + n] = *(const short8*)(ALL + L_WL + (48 + col) * 592 + n * 64 + q * 16);
        }

        for (int mt = w; mt < 49; mt += 12) {
            int p = mt * 16 + col;
            int y = p / 28, xx = p % 28;

            // p_conv for this 16-pixel tile (B from LDS pool rows 0..31)
            floatx4 a0 = {0.f, 0.f, 0.f, 0.f}, a1 = {0.f, 0.f, 0.f, 0.f};
#pragma unroll
            for (int n = 0; n < 9; n++) {
                int yy = y + n / 3 - 1, xc = xx + n % 3 - 1;
                bool ok = ((unsigned)yy < 28u) && ((unsigned)xc < 28u);
                int tp = ok ? (yy * 28 + xc) : 784;      // 784 = zero slot
                short8 a  = *(const short8*)(ib + tp * 64 + q * 16);
                short8 p0 = *(const short8*)(ALL + L_WL + col * 592 + n * 64 + q * 16);
                short8 p1 = *(const short8*)(ALL + L_WL + (16 + col) * 592 + n * 64 + q * 16);
                a0 = __builtin_amdgcn_mfma_f32_16x16x32_bf16(a, p0, a0, 0, 0, 0);
                a1 = __builtin_amdgcn_mfma_f32_16x16x32_bf16(a, p1, a1, 0, 0, 0);
            }
#pragma unroll
            for (int r = 0; r < 4; r++)
                otw[(q * 4 + r) * 18 + col] = a0[r] + bias0;
            if (col < 2) {
#pragma unroll
                for (int r = 0; r < 4; r++)
                    otw[(q * 4 + r) * 18 + 16 + col] = a1[r] + bias1;
            }
            __asm__ volatile("s_waitcnt lgkmcnt(0)" ::: "memory");

            floatx4 d0 = {0.f, 0.f, 0.f, 0.f}, d1 = {0.f, 0.f, 0.f, 0.f};
#pragma unroll
            for (int tg = 0; tg < 3; tg++) {
                // precompute: 48 combos (16 px x 3 taps), one per lane l<48
                if (l < 48) {
                    int px = l & 15, n = tg * 3 + (l >> 4);
                    int pg = mt * 16 + px;
                    int yg = pg / 28, xg = pg % 28;
                    float offy = otw[px * 18 + n];
                    float offx = otw[px * 18 + 9 + n];
                    float py = (float)(yg + n / 3) + offy;       // padded coords
                    float pxf = (float)(xg + n % 3) + offx;
                    float fy = floorf(py), fx = floorf(pxf);
                    float qy0 = fminf(fmaxf(fy, 0.f), 29.f);
                    float qy1 = fminf(fmaxf(fy + 1.f, 0.f), 29.f);
                    float qx0 = fminf(fmaxf(fx, 0.f), 29.f);
                    float qx1 = fminf(fmaxf(fx + 1.f, 0.f), 29.f);
                    float pyc = fminf(fmaxf(py, 0.f), 29.f);
                    float pxc = fminf(fmaxf(pxf, 0.f), 29.f);
                    float glt = (1.f + (qy0 - pyc)) * (1.f + (qx0 - pxc));
                    float grb = (1.f - (qy1 - pyc)) * (1.f - (qx1 - pxc));
                    float glb = (1.f + (qy0 - pyc)) * (1.f - (qx1 - pxc));
                    float grt = (1.f - (qy1 - pyc)) * (1.f + (qx0 - pxc));
                    int iy0 = (int)qy0, iy1 = (int)qy1, ix0 = (int)qx0, ix1 = (int)qx1;
                    int ly0 = iy0 - 1, ly1 = iy1 - 1, lx0 = ix0 - 1, lx1 = ix1 - 1;
                    bool v00 = ((unsigned)ly0 < 28u) && ((unsigned)lx0 < 28u);
                    bool v11 = ((unsigned)ly1 < 28u) && ((unsigned)lx1 < 28u);
                    bool v01 = ((unsigned)ly0 < 28u) && ((unsigned)lx1 < 28u);
                    bool v10 = ((unsigned)ly1 < 28u) && ((unsigned)lx0 < 28u);
                    unsigned p00 = v00 ? (unsigned)(ly0 * 28 + lx0) : 784u;
                    unsigned p11 = v11 ? (unsigned)(ly1 * 28 + lx1) : 784u;
                    unsigned p01 = v01 ? (unsigned)(ly0 * 28 + lx1) : 784u;
                    unsigned p10 = v10 ? (unsigned)(ly1 * 28 + lx0) : 784u;
                    uint4 rec = make_uint4(pkh(glt, grb), pkh(glb, grt),
                                           p00 | (p11 << 16), p01 | (p10 << 16));
                    *(uint4*)(gscr + l * 16) = rec;
                }
                __asm__ volatile("s_waitcnt lgkmcnt(0)" ::: "memory");

                // consume: 3 taps, record broadcast across quads
#pragma unroll
                for (int k3 = 0; k3 < 3; k3++) {
                    int n = tg * 3 + k3;
                    uint4 rec = *(const uint4*)(gscr + (k3 * 16 + col) * 16);
                    floatx2 gA = uph(rec.x), gB = uph(rec.y);
                    float glt = gA.x, grb = gA.y, glb = gB.x, grt = gB.y;
                    int p00 = (int)(rec.z & 0xffffu), p11 = (int)(rec.z >> 16);
                    int p01 = (int)(rec.w & 0xffffu), p10 = (int)(rec.w >> 16);
                    uint4 u00 = *(const uint4*)(ib + p00 * 64 + q * 16);
                    uint4 u11 = *(const uint4*)(ib + p11 * 64 + q * 16);
                    uint4 u01 = *(const uint4*)(ib + p01 * 64 + q * 16);
                    uint4 u10 = *(const uint4*)(ib + p10 * 64 + q * 16);
                    floatx2 f0 = up2(u00.x) * glt + up2(u11.x) * grb + up2(u01.x) * glb + up2(u10.x) * grt;
                    floatx2 f1 = up2(u00.y) * glt + up2(u11.y) * grb + up2(u01.y) * glb + up2(u10.y) * grt;
                    floatx2 f2 = up2(u00.z) * glt + up2(u11.z) * grb + up2(u01.z) * glb + up2(u10.z) * grt;
                    floatx2 f3 = up2(u00.w) * glt + up2(u11.w) * grb + up2(u01.w) * glb + up2(u10.w) * grt;
                    uint4 af4 = make_uint4(pk2bf(f0.x, f0.y), pk2bf(f1.x, f1.y),
                                           pk2bf(f2.x, f2.y), pk2bf(f3.x, f3.y));
                    short8 af = *(short8*)&af4;
                    d0 = __builtin_amdgcn_mfma_f32_16x16x32_bf16(af, b2fr[n], d0, 0, 0, 0);
                    d1 = __builtin_amdgcn_mfma_f32_16x16x32_bf16(af, b2fr[9 + n], d1, 0, 0, 0);
                }
            }
            // relu + shift2 + store to LDS uimg (interior layout, 64B/px)
#pragma unroll
            for (int r = 0; r < 4; r++) {
                int pout = mt * 16 + q * 4 + r;
                *(unsigned short*)(uimg + pout * 64 + col * 2) = f2bf(fmaxf(d0[r], 0.f) + sh0);
                *(unsigned short*)(uimg + pout * 64 + 32 + col * 2) = f2bf(fmaxf(d1[r], 0.f) + sh1);
            }
        }
    }
    __syncthreads();

    // ---- phase 3: stage w3 (bf16, pre-scaled) -> pool rows 0..63 (coalesced) ----
    {
        const uint4* src = (const uint4*)w3b;
        for (int i = t; i < 2304; i += 768) {
            int row = i / 36, g = i - row * 36;
            *(uint4*)(ALL + L_WL + row * 592 + g * 16) = src[row * 36 + g];
        }
    }
    __syncthreads();

    // ---- phase 4: conv3 MFMA + relu + global-sum partials (weights hoisted to VGPRs) ----
    {
        float* part = (float*)(ALL + L_OFFT);   // [12][32]
        int ocp = w & 1;
        const unsigned char* ib = uimg;

        short8 wfr[18];
#pragma unroll
        for (int n = 0; n < 9; n++) {
            wfr[n]     = *(const short8*)(ALL + L_WL + (ocp * 32 + col) * 592 + n * 64 + q * 16);
            wfr[9 + n] = *(const short8*)(ALL + L_WL + (ocp * 32 + 16 + col) * 592 + n * 64 + q * 16);
        }

        float psA = 0.f, psB = 0.f;
        for (int mt = (w >> 1); mt < 49; mt += 6) {
            int p = mt * 16 + col;
            int y = p / 28, xx = p % 28;
            floatx4 cA = {0.f, 0.f, 0.f, 0.f}, cB = {0.f, 0.f, 0.f, 0.f};
#pragma unroll
            for (int n = 0; n < 9; n++) {
                int yy = y + n / 3 - 1, xc = xx + n % 3 - 1;
                bool ok = ((unsigned)yy < 28u) && ((unsigned)xc < 28u);
                int tp = ok ? (yy * 28 + xc) : 784;
                short8 a = *(const short8*)(ib + tp * 64 + q * 16);
                cA = __builtin_amdgcn_mfma_f32_16x16x32_bf16(a, wfr[n], cA, 0, 0, 0);
                cB = __builtin_amdgcn_mfma_f32_16x16x32_bf16(a, wfr[9 + n], cB, 0, 0, 0);
            }
            psA += fmaxf(cA[0], 0.f) + fmaxf(cA[1], 0.f) + fmaxf(cA[2], 0.f) + fmaxf(cA[3], 0.f);
            psB += fmaxf(cB[0], 0.f) + fmaxf(cB[1], 0.f) + fmaxf(cB[2], 0.f) + fmaxf(cB[3], 0.f);
        }
        psA += __shfl_xor(psA, 16, 64); psA += __shfl_xor(psA, 32, 64);
        psB += __shfl_xor(psB, 16, 64); psB += __shfl_xor(psB, 32, 64);
        if (l < 16) { part[w * 32 + l] = psA; part[w * 32 + 16 + l] = psB; }
    }
    __syncthreads();

    // ---- phase 5: classifier (one wave): shift3, mean, linear 64->10, log_softmax ----
    if (t < 64) {
        const float* part = (const float*)(ALL + L_OFFT);
        int hi = t >> 5, c = t & 31;
        float s = 0.f;
#pragma unroll
        for (int j = 0; j < 6; j++) s += part[(2 * j + hi) * 32 + c];   // oc = t
        float feat = s * (1.f / 784.f) + c3s[t];
        float lg[10];
        float mx = -1e30f;
#pragma unroll
        for (int j = 0; j < 10; j++) {
            float v = feat * wc[j * 64 + t];
            v += __shfl_xor(v, 1, 64);  v += __shfl_xor(v, 2, 64);
            v += __shfl_xor(v, 4, 64);  v += __shfl_xor(v, 8, 64);
            v += __shfl_xor(v, 16, 64); v += __shfl_xor(v, 32, 64);
            lg[j] = v + bc[j];
            mx = fmaxf(mx, lg[j]);
        }
        float se = 0.f;
#pragma unroll
        for (int j = 0; j < 10; j++) se += expf(lg[j] - mx);
        float lse = logf(se);
#pragma unroll
        for (int j = 0; j < 10; j++)
            if (t == j) outp[(size_t)b * 10 + j] = lg[j] - mx - lse;
    }
}

extern "C" void kernel_launch(void* const* d_in, const int* in_sizes, int n_in,
                              void* d_out, int out_size, void* d_ws, size_t ws_size,
                              hipStream_t stream)
{
    (void)in_sizes; (void)n_in; (void)out_size; (void)ws_size;
    const float* x  = (const float*)d_in[0];
    const float* w1 = (const float*)d_in[1];
    const float* g1 = (const float*)d_in[2];
    const float* b1 = (const float*)d_in[3];
    const float* m1 = (const float*)d_in[4];
    const float* v1 = (const float*)d_in[5];
    const float* wp = (const float*)d_in[6];
    const float* bp = (const float*)d_in[7];
    const float* w2 = (const float*)d_in[8];
    const float* g2 = (const float*)d_in[9];
    const float* b2 = (const float*)d_in[10];
    const float* m2 = (const float*)d_in[11];
    const float* v2 = (const float*)d_in[12];
    const float* w3 = (const float*)d_in[13];
    const float* g3 = (const float*)d_in[14];
    const float* b3 = (const float*)d_in[15];
    const float* m3 = (const float*)d_in[16];
    const float* v3 = (const float*)d_in[17];
    const float* wc = (const float*)d_in[18];
    const float* bc = (const float*)d_in[19];
    float* outp = (float*)d_out;

    unsigned char* ws = (unsigned char*)d_ws;
    unsigned short* wpb = (unsigned short*)(ws + WPB_OFF);
    unsigned short* w2b = (unsigned short*)(ws + W2B_OFF);
    unsigned short* w3b = (unsigned short*)(ws + W3B_OFF);
    unsigned short* w1b = (unsigned short*)(ws + W1B_OFF);
    float* c1s = (float*)(ws + C1S_OFF);
    float* c2s = (float*)(ws + C2S_OFF);
    float* c3s = (float*)(ws + C3S_OFF);

    wcvt<<<149, 256, 0, stream>>>(wp, w2, w3, w1, g1, b1, m1, v1,
                                  g2, b2, m2, v2, g3, b3, m3, v3,
                                  wpb, w2b, w3b, w1b, c1s, c2s, c3s);
    meganet<<<NB, 768, 0, stream>>>(x, wpb, w2b, w3b, w1b, c1s, c2s, c3s,
                                    bp, wc, bc, outp);
}